// Round 24
// baseline (89.206 us; speedup 1.0000x reference)
//
#include <hip/hip_runtime.h>
#include <hip/hip_bf16.h>

// Problem constants
#define B_   32
#define N_   2048
#define E_   768
#define OUT_ 384
#define HID_ 16
constexpr int ROWS   = B_ * N_;      // 65536
constexpr int TILE_M = 32;           // rows per block (2 row-tiles of 16)
constexpr int NT     = OUT_ / 16;    // 24 N-tiles of local GEMM
constexpr int KT_L   = 6;            // 6 K-steps (local, K=192)
constexpr int KT_G   = 24;           // 24 K-steps (gate, K=768)
constexpr int S_AL   = 194;          // al row stride in shorts
constexpr int S_PL   = 392;          // pooled row stride in shorts

typedef __attribute__((ext_vector_type(8))) short bf16x8;
typedef __attribute__((ext_vector_type(4))) float f32x4;

__device__ __forceinline__ short f2bf(float f) {
  __hip_bfloat16 h = __float2bfloat16(f);          // RNE hardware cvt
  return __builtin_bit_cast(short, h);
}
__device__ __forceinline__ float bf2f(short s) {
  union { unsigned u; float f; } v; v.u = ((unsigned)(unsigned short)s) << 16;
  return v.f;
}

// deep async loads: issued where placed, cannot be sunk by the compiler
__device__ __forceinline__ void gload_pair(f32x4& d0, f32x4& d1, const float* a) {
  asm volatile("global_load_dwordx4 %0, %2, off\n\t"
               "global_load_dwordx4 %1, %2, off offset:16"
               : "=&v"(d0), "=&v"(d1)
               : "v"(a));
}
__device__ __forceinline__ void gload_frag(bf16x8& d, const short* a) {
  asm volatile("global_load_dwordx4 %0, %1, off" : "=&v"(d) : "v"(a));
}
#define WAITV(n) do { asm volatile("s_waitcnt vmcnt(" #n ")" ::: "memory"); \
                      __builtin_amdgcn_sched_barrier(0); } while (0)
// raw barrier: drains LDS ops only; vmem loads keep riding (8-phase pattern)
#define RAWBAR() do { __builtin_amdgcn_sched_barrier(0);                     \
                      asm volatile("s_waitcnt lgkmcnt(0)" ::: "memory");     \
                      __builtin_amdgcn_s_barrier();                          \
                      __builtin_amdgcn_sched_barrier(0); } while (0)

// Abramowitz-Stegun 7.1.25 (3-term), |err| <= 2.5e-5, branch-free (~9 VALU ops)
__device__ __forceinline__ float fast_erf(float x) {
  const float ax = __builtin_fabsf(x);
  const float t  = __builtin_amdgcn_rcpf(__builtin_fmaf(0.47047f, ax, 1.0f));
  float p = __builtin_fmaf(0.7478556f, t, -0.0958798f);
  p = __builtin_fmaf(p, t, 0.3480242f);
  const float e = __expf(-ax * ax);
  const float y = __builtin_fmaf(-p * t, e, 1.0f);
  return __builtin_copysignf(y, x);
}
__device__ __forceinline__ float gelu(float v) {
  return 0.5f * v * (1.0f + fast_erf(v * 0.70710678118654752f));
}

// ---------------- pre-pass: build bf16 MFMA B-fragments in workspace ----------------
__global__ void prep_kernel(const float* __restrict__ w_l, const float* __restrict__ w_g1,
                            short* __restrict__ wsL, short* __restrict__ wsG) {
  int t = blockIdx.x * blockDim.x + threadIdx.x;
  int wave = t >> 6, ln = t & 63;
  int kg = ln >> 4, c16 = ln & 15;
  if (wave < NT * KT_L) {
    int n = wave / KT_L, ks = wave % KT_L;
    bf16x8 v;
#pragma unroll
    for (int j = 0; j < 8; ++j) {
      int k = ks * 32 + kg * 8 + j;
      v[j] = f2bf(w_l[k * OUT_ + n * 16 + c16]);
    }
    *reinterpret_cast<bf16x8*>(&wsL[(size_t)(wave * 64 + ln) * 8]) = v;
  } else if (wave < NT * KT_L + KT_G) {
    int ks = wave - NT * KT_L;
    bf16x8 v;
#pragma unroll
    for (int j = 0; j < 8; ++j) {
      int k = ks * 32 + kg * 8 + j;
      v[j] = f2bf(w_g1[k * HID_ + c16]);
    }
    *reinterpret_cast<bf16x8*>(&wsG[(size_t)(ks * 64 + ln) * 8]) = v;
  }
}

// ---------------- main fused kernel: 256 threads = 4 waves own 32 rows ----------------
// Register-dieted schedule for (256,4): gate x-loads in a 4-slot rolling ring (depth
// 6-8), local GEMM triple-buffered 3-frag groups (3-group lookahead). 3 blocks/CU.
template <bool USE_WS>
__global__ __launch_bounds__(256, 4)
void spectre_kernel(const float* __restrict__ x,
                    const float* __restrict__ w_g1, const float* __restrict__ b_g1,
                    const float* __restrict__ ln_g_w, const float* __restrict__ ln_g_b,
                    const float* __restrict__ w_g2, const float* __restrict__ b_g2,
                    const float* __restrict__ w_l, const float* __restrict__ b_l,
                    const float* __restrict__ ln_l_w, const float* __restrict__ ln_l_b,
                    const short* __restrict__ wsL, const short* __restrict__ wsG,
                    float* __restrict__ out) {
  __shared__ short al[TILE_M * S_AL];    // 12416 B: local A (x[..., ::4] bf16)
  __shared__ short pl[TILE_M * S_PL];    // 25088 B: pooled (bf16)
  __shared__ float red2[4][16][17];      // 4352 B : gate partials per wave
  __shared__ float reds[4][32][2];       // 1024 B : local LN partials per wave
  __shared__ float gfl[32];              // 128 B  : per-row global feat

  const int tid = threadIdx.x;
  const int wv  = tid >> 6;        // wave 0..3
  const int wvp = wv >> 1;         // row-tile for gate (0: rows 0-15, 1: rows 16-31)
  const int wvk = wv & 1;          // K-half for gate
  const int ln  = tid & 63;
  const int kg  = ln >> 4;
  const int l15 = ln & 15;
  const int row0 = blockIdx.x * TILE_M;

  const float* xb = x + (size_t)(row0 + wvp * 16) * E_;

  // hoisted params (lwv/lbv deferred past B2 to cut gate-phase registers)
  const float bg  = b_g1[l15];
  const float lgw = ln_g_w[l15];
  const float lgb = ln_g_b[l15];
  const float wg2 = w_g2[l15];
  const float bg2 = b_g2[0];
  float blv[6];
#pragma unroll
  for (int j = 0; j < 6; ++j) blv[j] = b_l[(wv * 6 + j) * 16 + l15];
  const short* wlp = USE_WS ? (wsL + ((size_t)(wv * 6) * KT_L * 64 + ln) * 8) : nullptr;

  // ---- gate GEMM partial (rows wvp*16.., K-steps [12wvk,12wvk+12)) ----
  f32x4 accg = {0.f, 0.f, 0.f, 0.f};
  const int alr = (wvp * 16 + l15);   // al/pl row this lane stages
  if constexpr (USE_WS) {
    // gbv preloaded (L2), then drained; ring loads are asm-only afterwards
    bf16x8 gbv[12];
#pragma unroll
    for (int i = 0; i < 12; ++i)
      gbv[i] = *reinterpret_cast<const bf16x8*>(&wsG[((wvk * 12 + i) * 64 + ln) * 8]);

    asm volatile("s_waitcnt vmcnt(0)" ::: "memory");
    __builtin_amdgcn_sched_barrier(0);

    f32x4 x0[4], x1[4];
    const float* pA = xb + l15 * E_ + kg * 8;
#pragma unroll
    for (int s = 0; s < 4; ++s) gload_pair(x0[s], x1[s], pA + (wvk * 12 + s) * 32);

#define GSTEP(I, SLOT, WAIT)                                                          \
    do {                                                                              \
      WAITV(WAIT);                                                                    \
      const int ks = wvk * 12 + (I);                                                  \
      const f32x4 u0 = x0[SLOT], u1 = x1[SLOT];                                       \
      short2 lv;                                                                      \
      lv.x = f2bf(u0[0]);                                                             \
      lv.y = f2bf(u1[0]);                                                             \
      *reinterpret_cast<short2*>(&al[alr * S_AL + 8 * ks + 2 * kg]) = lv;             \
      short4 pv;                                                                      \
      pv.x = f2bf(0.5f * (u0[0] + u0[1]));                                            \
      pv.y = f2bf(0.5f * (u0[2] + u0[3]));                                            \
      pv.z = f2bf(0.5f * (u1[0] + u1[1]));                                            \
      pv.w = f2bf(0.5f * (u1[2] + u1[3]));                                            \
      *reinterpret_cast<short4*>(&pl[alr * S_PL + ks * 16 + kg * 4]) = pv;            \
      const bf16x8 a = { lv.x, f2bf(u0[1]), f2bf(u0[2]), f2bf(u0[3]),                 \
                         lv.y, f2bf(u1[1]), f2bf(u1[2]), f2bf(u1[3]) };               \
      accg = __builtin_amdgcn_mfma_f32_16x16x32_bf16(a, gbv[I], accg, 0, 0, 0);       \
      if ((I) + 4 < 12)                                                               \
        gload_pair(x0[SLOT], x1[SLOT], pA + (wvk * 12 + (I) + 4) * 32);               \
    } while (0)

    GSTEP(0, 0, 6);  GSTEP(1, 1, 6);  GSTEP(2, 2, 6);  GSTEP(3, 3, 6);
    GSTEP(4, 0, 6);  GSTEP(5, 1, 6);  GSTEP(6, 2, 6);  GSTEP(7, 3, 6);
    GSTEP(8, 0, 6);  GSTEP(9, 1, 4);  GSTEP(10, 2, 2); GSTEP(11, 3, 0);
#undef GSTEP
    __builtin_amdgcn_sched_barrier(0);
  } else {
    const float* pA = xb + l15 * E_ + kg * 8;
#pragma unroll
    for (int i = 0; i < 12; ++i) {
      const int ks = wvk * 12 + i;
      const float4 u0 = *reinterpret_cast<const float4*>(pA + ks * 32);
      const float4 u1 = *reinterpret_cast<const float4*>(pA + ks * 32 + 4);
      short2 lv;
      lv.x = f2bf(u0.x);
      lv.y = f2bf(u1.x);
      *reinterpret_cast<short2*>(&al[alr * S_AL + 8 * ks + 2 * kg]) = lv;
      short4 pv;
      pv.x = f2bf(0.5f * (u0.x + u0.y));
      pv.y = f2bf(0.5f * (u0.z + u0.w));
      pv.z = f2bf(0.5f * (u1.x + u1.y));
      pv.w = f2bf(0.5f * (u1.z + u1.w));
      *reinterpret_cast<short4*>(&pl[alr * S_PL + ks * 16 + kg * 4]) = pv;
      bf16x8 b;
#pragma unroll
      for (int j = 0; j < 8; ++j) b[j] = f2bf(w_g1[(ks * 32 + kg * 8 + j) * HID_ + l15]);
      const bf16x8 a = { lv.x, f2bf(u0.y), f2bf(u0.z), f2bf(u0.w),
                         lv.y, f2bf(u1.y), f2bf(u1.z), f2bf(u1.w) };
      accg = __builtin_amdgcn_mfma_f32_16x16x32_bf16(a, b, accg, 0, 0, 0);
    }
  }
#pragma unroll
  for (int r = 0; r < 4; ++r) red2[wv][kg * 4 + r][l15] = accg[r];

  // ---- B1: issue first 3 local frag groups (9 loads) so they ride the raw barrier ----
  bf16x8 fb0[3], fb1[3], fb2[3];
  if constexpr (USE_WS) {
#pragma unroll
    for (int j = 0; j < 3; ++j) gload_frag(fb0[j], wlp + ((0 + j) * 6 + 0) * 512);  // g0: ks0,h0
#pragma unroll
    for (int j = 0; j < 3; ++j) gload_frag(fb1[j], wlp + ((3 + j) * 6 + 0) * 512);  // g1: ks0,h1
#pragma unroll
    for (int j = 0; j < 3; ++j) gload_frag(fb2[j], wlp + ((0 + j) * 6 + 1) * 512);  // g2: ks1,h0
    RAWBAR();        // al/pl/red2 visible; 9 frag loads still in flight
  } else {
    __syncthreads();
  }

  // ---- local GEMM ----
  f32x4 acc0[6], acc1[6];
#pragma unroll
  for (int j = 0; j < 6; ++j) {
    acc0[j] = (f32x4){0.f, 0.f, 0.f, 0.f};
    acc1[j] = (f32x4){0.f, 0.f, 0.f, 0.f};
  }

  if constexpr (USE_WS) {
    // gate finalize under the frag-load latency (LDS + VALU only; no vmem)
    float gf[4];
#pragma unroll
    for (int r = 0; r < 4; ++r) {
      const int row = kg * 4 + r;
      const float y = red2[2 * wvp][row][l15] + red2[2 * wvp + 1][row][l15] + bg;
      float s = y, q = y * y;
#pragma unroll
      for (int m = 1; m < 16; m <<= 1) {
        s += __shfl_xor(s, m);
        q += __shfl_xor(q, m);
      }
      const float mean = s * (1.f / 16.f);
      const float var  = q * (1.f / 16.f) - mean * mean;
      const float rstd = rsqrtf(var + 1e-5f);
      const float vn = (y - mean) * rstd * lgw + lgb;
      float ps = gelu(vn) * wg2;
#pragma unroll
      for (int m = 1; m < 16; m <<= 1) ps += __shfl_xor(ps, m);
      gf[r] = ps + bg2;
    }
    if (wvk == 0 && l15 == 0) {
#pragma unroll
      for (int r = 0; r < 4; ++r) gfl[wvp * 16 + kg * 4 + r] = gf[r];
    }

    // ladder: 12 groups (K = ks*2+h), triple-buffered, 3-group lookahead
    bf16x8 aL0, aL1;
#define LSTEP(K, BUF, WAIT)                                                           \
    do {                                                                              \
      WAITV(WAIT);                                                                    \
      if (((K) & 1) == 0) {                                                           \
        aL0 = *reinterpret_cast<const bf16x8*>(                                       \
            &al[l15 * S_AL + ((K) >> 1) * 32 + kg * 8]);                              \
        aL1 = *reinterpret_cast<const bf16x8*>(                                       \
            &al[(16 + l15) * S_AL + ((K) >> 1) * 32 + kg * 8]);                       \
      }                                                                               \
      __builtin_amdgcn_s_setprio(1);                                                  \
      _Pragma("unroll")                                                               \
      for (int j = 0; j < 3; ++j) {                                                   \
        const int n = 3 * ((K) & 1) + j;                                              \
        acc0[n] = __builtin_amdgcn_mfma_f32_16x16x32_bf16(aL0, BUF[j], acc0[n], 0, 0, 0); \
        acc1[n] = __builtin_amdgcn_mfma_f32_16x16x32_bf16(aL1, BUF[j], acc1[n], 0, 0, 0); \
      }                                                                               \
      __builtin_amdgcn_s_setprio(0);                                                  \
      if ((K) + 3 < 12) {                                                             \
        _Pragma("unroll")                                                             \
        for (int j = 0; j < 3; ++j)                                                   \
          gload_frag(BUF[j],                                                          \
              wlp + ((3 * (((K) + 3) & 1) + j) * 6 + (((K) + 3) >> 1)) * 512);        \
      }                                                                               \
    } while (0)

    LSTEP(0,  fb0, 6);  LSTEP(1,  fb1, 6);  LSTEP(2,  fb2, 6);
    LSTEP(3,  fb0, 6);  LSTEP(4,  fb1, 6);  LSTEP(5,  fb2, 6);
    LSTEP(6,  fb0, 6);  LSTEP(7,  fb1, 6);  LSTEP(8,  fb2, 6);
    LSTEP(9,  fb0, 6);  LSTEP(10, fb1, 3);  LSTEP(11, fb2, 0);
#undef LSTEP
    __builtin_amdgcn_sched_barrier(0);
  } else {
    float gf[4];
#pragma unroll
    for (int r = 0; r < 4; ++r) {
      const int row = kg * 4 + r;
      const float y = red2[2 * wvp][row][l15] + red2[2 * wvp + 1][row][l15] + bg;
      float s = y, q = y * y;
#pragma unroll
      for (int m = 1; m < 16; m <<= 1) { s += __shfl_xor(s, m); q += __shfl_xor(q, m); }
      const float mean = s * (1.f / 16.f);
      const float var  = q * (1.f / 16.f) - mean * mean;
      const float rstd = rsqrtf(var + 1e-5f);
      const float vn = (y - mean) * rstd * lgw + lgb;
      float ps = gelu(vn) * wg2;
#pragma unroll
      for (int m = 1; m < 16; m <<= 1) ps += __shfl_xor(ps, m);
      gf[r] = ps + bg2;
    }
    if (wvk == 0 && l15 == 0) {
#pragma unroll
      for (int r = 0; r < 4; ++r) gfl[wvp * 16 + kg * 4 + r] = gf[r];
    }
#pragma unroll
    for (int ks = 0; ks < KT_L; ++ks) {
      const bf16x8 aL0 = *reinterpret_cast<const bf16x8*>(&al[l15 * S_AL + ks * 32 + kg * 8]);
      const bf16x8 aL1 = *reinterpret_cast<const bf16x8*>(&al[(16 + l15) * S_AL + ks * 32 + kg * 8]);
#pragma unroll
      for (int j = 0; j < 6; ++j) {
        const int ng = wv * 6 + j;
        bf16x8 b;
#pragma unroll
        for (int jj = 0; jj < 8; ++jj)
          b[jj] = f2bf(w_l[(ks * 32 + kg * 8 + jj) * OUT_ + ng * 16 + l15]);
        acc0[j] = __builtin_amdgcn_mfma_f32_16x16x32_bf16(aL0, b, acc0[j], 0, 0, 0);
        acc1[j] = __builtin_amdgcn_mfma_f32_16x16x32_bf16(aL1, b, acc1[j], 0, 0, 0);
      }
    }
  }

  // ---- add b_l, LN stats over this wave's 96 cols for BOTH row-tiles ----
  float s10[4] = {0.f, 0.f, 0.f, 0.f}, s20[4] = {0.f, 0.f, 0.f, 0.f};
  float s11[4] = {0.f, 0.f, 0.f, 0.f}, s21[4] = {0.f, 0.f, 0.f, 0.f};
#pragma unroll
  for (int j = 0; j < 6; ++j) {
#pragma unroll
    for (int r = 0; r < 4; ++r) {
      const float v0 = acc0[j][r] + blv[j];
      acc0[j][r] = v0;
      s10[r] += v0; s20[r] += v0 * v0;
      const float v1 = acc1[j][r] + blv[j];
      acc1[j][r] = v1;
      s11[r] += v1; s21[r] += v1 * v1;
    }
  }
#pragma unroll
  for (int m = 1; m < 16; m <<= 1) {
#pragma unroll
    for (int r = 0; r < 4; ++r) {
      s10[r] += __shfl_xor(s10[r], m);
      s20[r] += __shfl_xor(s20[r], m);
      s11[r] += __shfl_xor(s11[r], m);
      s21[r] += __shfl_xor(s21[r], m);
    }
  }
  if (l15 == 0) {
#pragma unroll
    for (int r = 0; r < 4; ++r) {
      reds[wv][kg * 4 + r][0] = s10[r];
      reds[wv][kg * 4 + r][1] = s20[r];
      reds[wv][16 + kg * 4 + r][0] = s11[r];
      reds[wv][16 + kg * 4 + r][1] = s21[r];
    }
  }
  if constexpr (USE_WS) {
    RAWBAR();        // B2: reds + gfl visible
  } else {
    __syncthreads();
  }

  // deferred LN-local params (L2-hot; loaded after B2, latency hidden by LN math)
  float lwv[6], lbv[6];
#pragma unroll
  for (int j = 0; j < 6; ++j) {
    const int col = (wv * 6 + j) * 16 + l15;
    lwv[j] = ln_l_w[col];
    lbv[j] = ln_l_b[col];
  }

  // ---- local finalize: LN over 384 (4-wave combine), GeLU, + pooled + gate; store ----
  float mean0[4], rstd0[4], mean1[4], rstd1[4];
#pragma unroll
  for (int r = 0; r < 4; ++r) {
    const int row = kg * 4 + r;
    float t1 = reds[0][row][0] + reds[1][row][0] + reds[2][row][0] + reds[3][row][0];
    float t2 = reds[0][row][1] + reds[1][row][1] + reds[2][row][1] + reds[3][row][1];
    mean0[r] = t1 * (1.f / 384.f);
    rstd0[r] = rsqrtf(t2 * (1.f / 384.f) - mean0[r] * mean0[r] + 1e-5f);
    t1 = reds[0][16 + row][0] + reds[1][16 + row][0] + reds[2][16 + row][0] + reds[3][16 + row][0];
    t2 = reds[0][16 + row][1] + reds[1][16 + row][1] + reds[2][16 + row][1] + reds[3][16 + row][1];
    mean1[r] = t1 * (1.f / 384.f);
    rstd1[r] = rsqrtf(t2 * (1.f / 384.f) - mean1[r] * mean1[r] + 1e-5f);
  }
#pragma unroll
  for (int n = 0; n < 6; ++n) {
    const int col = (wv * 6 + n) * 16 + l15;
#pragma unroll
    for (int r = 0; r < 4; ++r) {
      const int rowA = kg * 4 + r;
      {
        const float pooled = bf2f(pl[rowA * S_PL + col]);
        const float vn = (acc0[n][r] - mean0[r]) * rstd0[r] * lwv[n] + lbv[n];
        out[(size_t)(row0 + rowA) * OUT_ + col] = gelu(vn) + gfl[rowA] + pooled;
      }
      {
        const int rowB = 16 + rowA;
        const float pooled = bf2f(pl[rowB * S_PL + col]);
        const float vn = (acc1[n][r] - mean1[r]) * rstd1[r] * lwv[n] + lbv[n];
        out[(size_t)(row0 + rowB) * OUT_ + col] = gelu(vn) + gfl[rowB] + pooled;
      }
    }
  }
}

// ---------------- launch ----------------
extern "C" void kernel_launch(void* const* d_in, const int* in_sizes, int n_in,
                              void* d_out, int out_size, void* d_ws, size_t ws_size,
                              hipStream_t stream) {
  (void)in_sizes; (void)n_in; (void)out_size;
  const float* x      = (const float*)d_in[0];
  const float* w_g1   = (const float*)d_in[1];
  const float* b_g1   = (const float*)d_in[2];
  const float* ln_g_w = (const float*)d_in[3];
  const float* ln_g_b = (const float*)d_in[4];
  const float* w_g2   = (const float*)d_in[5];
  const float* b_g2   = (const float*)d_in[6];
  const float* w_l    = (const float*)d_in[7];
  const float* b_l    = (const float*)d_in[8];
  const float* ln_l_w = (const float*)d_in[9];
  const float* ln_l_b = (const float*)d_in[10];
  float* out = (float*)d_out;

  const size_t needL = (size_t)NT * KT_L * 64 * 8;   // shorts
  const size_t needG = (size_t)KT_G * 64 * 8;        // shorts
  const bool use_ws = ws_size >= (needL + needG) * sizeof(short);

  short* wsL = (short*)d_ws;
  short* wsG = wsL + needL;

  const int grid = ROWS / TILE_M;   // 2048
  if (use_ws) {
    prep_kernel<<<(NT * KT_L + KT_G) * 64 / 256, 256, 0, stream>>>(w_l, w_g1, wsL, wsG);
    spectre_kernel<true><<<grid, 256, 0, stream>>>(x, w_g1, b_g1, ln_g_w, ln_g_b, w_g2, b_g2,
                                                   w_l, b_l, ln_l_w, ln_l_b, wsL, wsG, out);
  } else {
    spectre_kernel<false><<<grid, 256, 0, stream>>>(x, w_g1, b_g1, ln_g_w, ln_g_b, w_g2, b_g2,
                                                    w_l, b_l, ln_l_w, ln_l_b, nullptr, nullptr, out);
  }
}

// Round 25
// 87.040 us; speedup vs baseline: 1.0249x; 1.0249x over previous
//
#include <hip/hip_runtime.h>
#include <hip/hip_bf16.h>

// Problem constants
#define B_   32
#define N_   2048
#define E_   768
#define OUT_ 384
#define HID_ 16
constexpr int ROWS   = B_ * N_;      // 65536
constexpr int TILE_M = 32;           // rows per block (2 row-tiles of 16)
constexpr int NT     = OUT_ / 16;    // 24 N-tiles of local GEMM
constexpr int KT_L   = 6;            // 6 K-steps (local, K=192)
constexpr int KT_G   = 24;           // 24 K-steps (gate, K=768)
constexpr int S_AL   = 194;          // al row stride in shorts
constexpr int S_PL   = 392;          // pooled row stride in shorts

typedef __attribute__((ext_vector_type(8))) short bf16x8;
typedef __attribute__((ext_vector_type(4))) float f32x4;

__device__ __forceinline__ short f2bf(float f) {
  __hip_bfloat16 h = __float2bfloat16(f);          // RNE hardware cvt
  return __builtin_bit_cast(short, h);
}
__device__ __forceinline__ float bf2f(short s) {
  union { unsigned u; float f; } v; v.u = ((unsigned)(unsigned short)s) << 16;
  return v.f;
}

// deep async loads: issued where placed, cannot be sunk by the compiler
__device__ __forceinline__ void gload_pair(f32x4& d0, f32x4& d1, const float* a) {
  asm volatile("global_load_dwordx4 %0, %2, off\n\t"
               "global_load_dwordx4 %1, %2, off offset:16"
               : "=&v"(d0), "=&v"(d1)
               : "v"(a));
}
__device__ __forceinline__ void gload_frag(bf16x8& d, const short* a) {
  asm volatile("global_load_dwordx4 %0, %1, off" : "=&v"(d) : "v"(a));
}
#define WAITV(n) do { asm volatile("s_waitcnt vmcnt(" #n ")" ::: "memory"); \
                      __builtin_amdgcn_sched_barrier(0); } while (0)

// Abramowitz-Stegun 7.1.25 (3-term), |err| <= 2.5e-5, branch-free (~9 VALU ops)
__device__ __forceinline__ float fast_erf(float x) {
  const float ax = __builtin_fabsf(x);
  const float t  = __builtin_amdgcn_rcpf(__builtin_fmaf(0.47047f, ax, 1.0f));
  float p = __builtin_fmaf(0.7478556f, t, -0.0958798f);
  p = __builtin_fmaf(p, t, 0.3480242f);
  const float e = __expf(-ax * ax);
  const float y = __builtin_fmaf(-p * t, e, 1.0f);
  return __builtin_copysignf(y, x);
}
__device__ __forceinline__ float gelu(float v) {
  return 0.5f * v * (1.0f + fast_erf(v * 0.70710678118654752f));
}

// ---------------- pre-pass: build bf16 MFMA B-fragments in workspace ----------------
__global__ void prep_kernel(const float* __restrict__ w_l, const float* __restrict__ w_g1,
                            short* __restrict__ wsL, short* __restrict__ wsG) {
  int t = blockIdx.x * blockDim.x + threadIdx.x;
  int wave = t >> 6, ln = t & 63;
  int kg = ln >> 4, c16 = ln & 15;
  if (wave < NT * KT_L) {
    int n = wave / KT_L, ks = wave % KT_L;
    bf16x8 v;
#pragma unroll
    for (int j = 0; j < 8; ++j) {
      int k = ks * 32 + kg * 8 + j;
      v[j] = f2bf(w_l[k * OUT_ + n * 16 + c16]);
    }
    *reinterpret_cast<bf16x8*>(&wsL[(size_t)(wave * 64 + ln) * 8]) = v;
  } else if (wave < NT * KT_L + KT_G) {
    int ks = wave - NT * KT_L;
    bf16x8 v;
#pragma unroll
    for (int j = 0; j < 8; ++j) {
      int k = ks * 32 + kg * 8 + j;
      v[j] = f2bf(w_g1[k * HID_ + c16]);
    }
    *reinterpret_cast<bf16x8*>(&wsG[(size_t)(ks * 64 + ln) * 8]) = v;
  }
}

// ---------------- main fused kernel: 256 threads = 4 waves own 32 rows ----------------
// Gate: wave (wvp,wvk) does rows [wvp*16,+16) x K-half wvk (asm burst). Local GEMM:
// wave wv does n-tiles [wv*6,+6) for BOTH row-tiles -> each B-frag feeds 2 MFMAs.
// NOTE: (256,2) is load-bearing: any lower VGPR cap (84 @ (256,3)) spills the frag
// burst (R19: WRITE 175MB). Occupancy is NOT the lever (R17/R19/R24 proved).
template <bool USE_WS>
__global__ __launch_bounds__(256, 2)
void spectre_kernel(const float* __restrict__ x,
                    const float* __restrict__ w_g1, const float* __restrict__ b_g1,
                    const float* __restrict__ ln_g_w, const float* __restrict__ ln_g_b,
                    const float* __restrict__ w_g2, const float* __restrict__ b_g2,
                    const float* __restrict__ w_l, const float* __restrict__ b_l,
                    const float* __restrict__ ln_l_w, const float* __restrict__ ln_l_b,
                    const short* __restrict__ wsL, const short* __restrict__ wsG,
                    float* __restrict__ out) {
  __shared__ short al[TILE_M * S_AL];    // 12416 B: local A (x[..., ::4] bf16)
  __shared__ short pl[TILE_M * S_PL];    // 25088 B: pooled (bf16)
  __shared__ float red2[4][16][17];      // 4352 B : gate partials per wave
  __shared__ float reds[4][32][2];       // 1024 B : local LN partials per wave
  __shared__ float gfl[32];              // 128 B  : per-row global feat

  const int tid = threadIdx.x;
  const int wv  = tid >> 6;        // wave 0..3
  const int wvp = wv >> 1;         // row-tile for gate (0: rows 0-15, 1: rows 16-31)
  const int wvk = wv & 1;          // K-half for gate
  const int ln  = tid & 63;
  const int kg  = ln >> 4;
  const int l15 = ln & 15;
  const int row0 = blockIdx.x * TILE_M;

  const float* xb = x + (size_t)(row0 + wvp * 16) * E_;

  // hoisted params (drained before asm regions)
  const float bg  = b_g1[l15];
  const float lgw = ln_g_w[l15];
  const float lgb = ln_g_b[l15];
  const float wg2 = w_g2[l15];
  const float bg2 = b_g2[0];
  float blv[6], lwv[6], lbv[6];
#pragma unroll
  for (int j = 0; j < 6; ++j) {
    const int col = (wv * 6 + j) * 16 + l15;
    blv[j] = b_l[col];
    lwv[j] = ln_l_w[col];
    lbv[j] = ln_l_b[col];
  }

  // ---- gate GEMM partial (rows wvp*16.., K-steps [12wvk,12wvk+12)), asm burst ----
  f32x4 accg = {0.f, 0.f, 0.f, 0.f};
  const int alr = (wvp * 16 + l15);   // al/pl row this lane stages
  if constexpr (USE_WS) {
    bf16x8 gbv[12];
#pragma unroll
    for (int i = 0; i < 12; ++i)
      gbv[i] = *reinterpret_cast<const bf16x8*>(&wsG[((wvk * 12 + i) * 64 + ln) * 8]);

    asm volatile("s_waitcnt vmcnt(0)" ::: "memory");
    __builtin_amdgcn_sched_barrier(0);

    f32x4 xa0[6], xa1[6], xb0[6], xb1[6];
    const float* pA = xb + l15 * E_ + kg * 8;
#pragma unroll
    for (int i = 0; i < 6; ++i) gload_pair(xa0[i], xa1[i], pA + (wvk * 12 + i) * 32);
#pragma unroll
    for (int i = 0; i < 6; ++i) gload_pair(xb0[i], xb1[i], pA + (wvk * 12 + 6 + i) * 32);

    WAITV(12);
#pragma unroll
    for (int i = 0; i < 6; ++i) {
      const int ks = wvk * 12 + i;
      const f32x4 u0 = xa0[i], u1 = xa1[i];
      short2 lv;
      lv.x = f2bf(u0[0]);
      lv.y = f2bf(u1[0]);
      *reinterpret_cast<short2*>(&al[alr * S_AL + 8 * ks + 2 * kg]) = lv;
      short4 pv;
      pv.x = f2bf(0.5f * (u0[0] + u0[1]));
      pv.y = f2bf(0.5f * (u0[2] + u0[3]));
      pv.z = f2bf(0.5f * (u1[0] + u1[1]));
      pv.w = f2bf(0.5f * (u1[2] + u1[3]));
      *reinterpret_cast<short4*>(&pl[alr * S_PL + ks * 16 + kg * 4]) = pv;
      const bf16x8 a = { lv.x, f2bf(u0[1]), f2bf(u0[2]), f2bf(u0[3]),
                         lv.y, f2bf(u1[1]), f2bf(u1[2]), f2bf(u1[3]) };
      accg = __builtin_amdgcn_mfma_f32_16x16x32_bf16(a, gbv[i], accg, 0, 0, 0);
    }
    WAITV(0);
#pragma unroll
    for (int i = 0; i < 6; ++i) {
      const int ks = wvk * 12 + 6 + i;
      const f32x4 u0 = xb0[i], u1 = xb1[i];
      short2 lv;
      lv.x = f2bf(u0[0]);
      lv.y = f2bf(u1[0]);
      *reinterpret_cast<short2*>(&al[alr * S_AL + 8 * ks + 2 * kg]) = lv;
      short4 pv;
      pv.x = f2bf(0.5f * (u0[0] + u0[1]));
      pv.y = f2bf(0.5f * (u0[2] + u0[3]));
      pv.z = f2bf(0.5f * (u1[0] + u1[1]));
      pv.w = f2bf(0.5f * (u1[2] + u1[3]));
      *reinterpret_cast<short4*>(&pl[alr * S_PL + ks * 16 + kg * 4]) = pv;
      const bf16x8 a = { lv.x, f2bf(u0[1]), f2bf(u0[2]), f2bf(u0[3]),
                         lv.y, f2bf(u1[1]), f2bf(u1[2]), f2bf(u1[3]) };
      accg = __builtin_amdgcn_mfma_f32_16x16x32_bf16(a, gbv[6 + i], accg, 0, 0, 0);
    }
    __builtin_amdgcn_sched_barrier(0);
  } else {
    const float* pA = xb + l15 * E_ + kg * 8;
#pragma unroll
    for (int i = 0; i < 12; ++i) {
      const int ks = wvk * 12 + i;
      const float4 u0 = *reinterpret_cast<const float4*>(pA + ks * 32);
      const float4 u1 = *reinterpret_cast<const float4*>(pA + ks * 32 + 4);
      short2 lv;
      lv.x = f2bf(u0.x);
      lv.y = f2bf(u1.x);
      *reinterpret_cast<short2*>(&al[alr * S_AL + 8 * ks + 2 * kg]) = lv;
      short4 pv;
      pv.x = f2bf(0.5f * (u0.x + u0.y));
      pv.y = f2bf(0.5f * (u0.z + u0.w));
      pv.z = f2bf(0.5f * (u1.x + u1.y));
      pv.w = f2bf(0.5f * (u1.z + u1.w));
      *reinterpret_cast<short4*>(&pl[alr * S_PL + ks * 16 + kg * 4]) = pv;
      bf16x8 b;
#pragma unroll
      for (int j = 0; j < 8; ++j) b[j] = f2bf(w_g1[(ks * 32 + kg * 8 + j) * HID_ + l15]);
      const bf16x8 a = { lv.x, f2bf(u0.y), f2bf(u0.z), f2bf(u0.w),
                         lv.y, f2bf(u1.y), f2bf(u1.z), f2bf(u1.w) };
      accg = __builtin_amdgcn_mfma_f32_16x16x32_bf16(a, b, accg, 0, 0, 0);
    }
  }
#pragma unroll
  for (int r = 0; r < 4; ++r) red2[wv][kg * 4 + r][l15] = accg[r];

  __syncthreads();   // B1: al/pl/red2 visible

  // ---- local GEMM: frag reuse across both row-tiles; asm ladder 6 loads / 12 MFMAs ----
  f32x4 acc0[6], acc1[6];
#pragma unroll
  for (int j = 0; j < 6; ++j) {
    acc0[j] = (f32x4){0.f, 0.f, 0.f, 0.f};
    acc1[j] = (f32x4){0.f, 0.f, 0.f, 0.f};
  }

  if constexpr (USE_WS) {
    const short* wlp = wsL + ((size_t)(wv * 6) * KT_L * 64 + ln) * 8;
    bf16x8 fA[6], fB[6];
#pragma unroll
    for (int j = 0; j < 6; ++j) gload_frag(fA[j], wlp + (j * 6 + 0) * 512);
#pragma unroll
    for (int j = 0; j < 6; ++j) gload_frag(fB[j], wlp + (j * 6 + 1) * 512);
    __builtin_amdgcn_sched_barrier(0);

    // gate finalize under the frag-load latency (LDS + VALU only; no vmem)
    float gf[4];
#pragma unroll
    for (int r = 0; r < 4; ++r) {
      const int row = kg * 4 + r;
      const float y = red2[2 * wvp][row][l15] + red2[2 * wvp + 1][row][l15] + bg;
      float s = y, q = y * y;
#pragma unroll
      for (int m = 1; m < 16; m <<= 1) {
        s += __shfl_xor(s, m);
        q += __shfl_xor(q, m);
      }
      const float mean = s * (1.f / 16.f);
      const float var  = q * (1.f / 16.f) - mean * mean;
      const float rstd = rsqrtf(var + 1e-5f);
      const float vn = (y - mean) * rstd * lgw + lgb;
      float ps = gelu(vn) * wg2;
#pragma unroll
      for (int m = 1; m < 16; m <<= 1) ps += __shfl_xor(ps, m);
      gf[r] = ps + bg2;
    }
    if (wvk == 0 && l15 == 0) {
#pragma unroll
      for (int r = 0; r < 4; ++r) gfl[wvp * 16 + kg * 4 + r] = gf[r];
    }

#define LKSTEP(KS, FREG, NEXTKS, NEXTREG, LASTWAIT)                                   \
    do {                                                                              \
      WAITV(LASTWAIT);                                                                \
      const bf16x8 aL0 = *reinterpret_cast<const bf16x8*>(                            \
          &al[l15 * S_AL + (KS) * 32 + kg * 8]);                                      \
      const bf16x8 aL1 = *reinterpret_cast<const bf16x8*>(                            \
          &al[(16 + l15) * S_AL + (KS) * 32 + kg * 8]);                               \
      _Pragma("unroll")                                                               \
      for (int j = 0; j < 6; ++j) {                                                   \
        acc0[j] = __builtin_amdgcn_mfma_f32_16x16x32_bf16(aL0, FREG[j], acc0[j], 0, 0, 0); \
        acc1[j] = __builtin_amdgcn_mfma_f32_16x16x32_bf16(aL1, FREG[j], acc1[j], 0, 0, 0); \
      }                                                                               \
      if ((NEXTKS) < KT_L) {                                                          \
        _Pragma("unroll")                                                             \
        for (int j = 0; j < 6; ++j)                                                   \
          gload_frag(NEXTREG[j], wlp + (j * 6 + (NEXTKS)) * 512);                     \
      }                                                                               \
    } while (0)

    LKSTEP(0, fA, 2, fA, 6);
    LKSTEP(1, fB, 3, fB, 6);
    LKSTEP(2, fA, 4, fA, 6);
    LKSTEP(3, fB, 5, fB, 6);
    LKSTEP(4, fA, 6, fA, 6);
    LKSTEP(5, fB, 6, fB, 0);
#undef LKSTEP
    __builtin_amdgcn_sched_barrier(0);
  } else {
    // gate finalize
    float gf[4];
#pragma unroll
    for (int r = 0; r < 4; ++r) {
      const int row = kg * 4 + r;
      const float y = red2[2 * wvp][row][l15] + red2[2 * wvp + 1][row][l15] + bg;
      float s = y, q = y * y;
#pragma unroll
      for (int m = 1; m < 16; m <<= 1) { s += __shfl_xor(s, m); q += __shfl_xor(q, m); }
      const float mean = s * (1.f / 16.f);
      const float var  = q * (1.f / 16.f) - mean * mean;
      const float rstd = rsqrtf(var + 1e-5f);
      const float vn = (y - mean) * rstd * lgw + lgb;
      float ps = gelu(vn) * wg2;
#pragma unroll
      for (int m = 1; m < 16; m <<= 1) ps += __shfl_xor(ps, m);
      gf[r] = ps + bg2;
    }
    if (wvk == 0 && l15 == 0) {
#pragma unroll
      for (int r = 0; r < 4; ++r) gfl[wvp * 16 + kg * 4 + r] = gf[r];
    }
#pragma unroll
    for (int ks = 0; ks < KT_L; ++ks) {
      const bf16x8 aL0 = *reinterpret_cast<const bf16x8*>(&al[l15 * S_AL + ks * 32 + kg * 8]);
      const bf16x8 aL1 = *reinterpret_cast<const bf16x8*>(&al[(16 + l15) * S_AL + ks * 32 + kg * 8]);
#pragma unroll
      for (int j = 0; j < 6; ++j) {
        const int ng = wv * 6 + j;
        bf16x8 b;
#pragma unroll
        for (int jj = 0; jj < 8; ++jj)
          b[jj] = f2bf(w_l[(ks * 32 + kg * 8 + jj) * OUT_ + ng * 16 + l15]);
        acc0[j] = __builtin_amdgcn_mfma_f32_16x16x32_bf16(aL0, b, acc0[j], 0, 0, 0);
        acc1[j] = __builtin_amdgcn_mfma_f32_16x16x32_bf16(aL1, b, acc1[j], 0, 0, 0);
      }
    }
  }

  // ---- add b_l, LN stats over this wave's 96 cols for BOTH row-tiles ----
  float s10[4] = {0.f, 0.f, 0.f, 0.f}, s20[4] = {0.f, 0.f, 0.f, 0.f};
  float s11[4] = {0.f, 0.f, 0.f, 0.f}, s21[4] = {0.f, 0.f, 0.f, 0.f};
#pragma unroll
  for (int j = 0; j < 6; ++j) {
#pragma unroll
    for (int r = 0; r < 4; ++r) {
      const float v0 = acc0[j][r] + blv[j];
      acc0[j][r] = v0;
      s10[r] += v0; s20[r] += v0 * v0;
      const float v1 = acc1[j][r] + blv[j];
      acc1[j][r] = v1;
      s11[r] += v1; s21[r] += v1 * v1;
    }
  }
#pragma unroll
  for (int m = 1; m < 16; m <<= 1) {
#pragma unroll
    for (int r = 0; r < 4; ++r) {
      s10[r] += __shfl_xor(s10[r], m);
      s20[r] += __shfl_xor(s20[r], m);
      s11[r] += __shfl_xor(s11[r], m);
      s21[r] += __shfl_xor(s21[r], m);
    }
  }
  if (l15 == 0) {
#pragma unroll
    for (int r = 0; r < 4; ++r) {
      reds[wv][kg * 4 + r][0] = s10[r];
      reds[wv][kg * 4 + r][1] = s20[r];
      reds[wv][16 + kg * 4 + r][0] = s11[r];
      reds[wv][16 + kg * 4 + r][1] = s21[r];
    }
  }
  __syncthreads();   // B2: reds + gfl visible

  // ---- local finalize: LN over 384 (4-wave combine), GeLU, + pooled + gate; store ----
  float mean0[4], rstd0[4], mean1[4], rstd1[4];
#pragma unroll
  for (int r = 0; r < 4; ++r) {
    const int row = kg * 4 + r;
    float t1 = reds[0][row][0] + reds[1][row][0] + reds[2][row][0] + reds[3][row][0];
    float t2 = reds[0][row][1] + reds[1][row][1] + reds[2][row][1] + reds[3][row][1];
    mean0[r] = t1 * (1.f / 384.f);
    rstd0[r] = rsqrtf(t2 * (1.f / 384.f) - mean0[r] * mean0[r] + 1e-5f);
    t1 = reds[0][16 + row][0] + reds[1][16 + row][0] + reds[2][16 + row][0] + reds[3][16 + row][0];
    t2 = reds[0][16 + row][1] + reds[1][16 + row][1] + reds[2][16 + row][1] + reds[3][16 + row][1];
    mean1[r] = t1 * (1.f / 384.f);
    rstd1[r] = rsqrtf(t2 * (1.f / 384.f) - mean1[r] * mean1[r] + 1e-5f);
  }
#pragma unroll
  for (int n = 0; n < 6; ++n) {
    const int col = (wv * 6 + n) * 16 + l15;
#pragma unroll
    for (int r = 0; r < 4; ++r) {
      const int rowA = kg * 4 + r;
      {
        const float pooled = bf2f(pl[rowA * S_PL + col]);
        const float vn = (acc0[n][r] - mean0[r]) * rstd0[r] * lwv[n] + lbv[n];
        out[(size_t)(row0 + rowA) * OUT_ + col] = gelu(vn) + gfl[rowA] + pooled;
      }
      {
        const int rowB = 16 + rowA;
        const float pooled = bf2f(pl[rowB * S_PL + col]);
        const float vn = (acc1[n][r] - mean1[r]) * rstd1[r] * lwv[n] + lbv[n];
        out[(size_t)(row0 + rowB) * OUT_ + col] = gelu(vn) + gfl[rowB] + pooled;
      }
    }
  }
}

// ---------------- launch ----------------
extern "C" void kernel_launch(void* const* d_in, const int* in_sizes, int n_in,
                              void* d_out, int out_size, void* d_ws, size_t ws_size,
                              hipStream_t stream) {
  (void)in_sizes; (void)n_in; (void)out_size;
  const float* x      = (const float*)d_in[0];
  const float* w_g1   = (const float*)d_in[1];
  const float* b_g1   = (const float*)d_in[2];
  const float* ln_g_w = (const float*)d_in[3];
  const float* ln_g_b = (const float*)d_in[4];
  const float* w_g2   = (const float*)d_in[5];
  const float* b_g2   = (const float*)d_in[6];
  const float* w_l    = (const float*)d_in[7];
  const float* b_l    = (const float*)d_in[8];
  const float* ln_l_w = (const float*)d_in[9];
  const float* ln_l_b = (const float*)d_in[10];
  float* out = (float*)d_out;

  const size_t needL = (size_t)NT * KT_L * 64 * 8;   // shorts
  const size_t needG = (size_t)KT_G * 64 * 8;        // shorts
  const bool use_ws = ws_size >= (needL + needG) * sizeof(short);

  short* wsL = (short*)d_ws;
  short* wsG = wsL + needL;

  const int grid = ROWS / TILE_M;   // 2048
  if (use_ws) {
    prep_kernel<<<(NT * KT_L + KT_G) * 64 / 256, 256, 0, stream>>>(w_l, w_g1, wsL, wsG);
    spectre_kernel<true><<<grid, 256, 0, stream>>>(x, w_g1, b_g1, ln_g_w, ln_g_b, w_g2, b_g2,
                                                   w_l, b_l, ln_l_w, ln_l_b, wsL, wsG, out);
  } else {
    spectre_kernel<false><<<grid, 256, 0, stream>>>(x, w_g1, b_g1, ln_g_w, ln_g_b, w_g2, b_g2,
                                                    w_l, b_l, ln_l_w, ln_l_b, nullptr, nullptr, out);
  }
}